// Round 1
// 125.432 us; speedup vs baseline: 1.0385x; 1.0385x over previous
//
#include <hip/hip_runtime.h>

#define N_NODES 50000
#define IN_CH   256
#define HID_CH  64
#define N_EDGES 800000

#define AG_ROWS 64           // nodes per bucket
#define NBUCKET 782          // ceil(50000 / 64)
#define CAPB    1536         // fixed capacity per bucket region (~16 sigma)
#define PTILE   4096         // edges per partition tile
#define NPT     196          // ceil(800000 / 4096)
#define GEMM_BLOCKS 391      // ceil(50000 / 128) at 128 rows per 512-thr block
#define CAP     2048         // aggregate staging capacity (> CAPB)

typedef __attribute__((ext_vector_type(8))) short short8;
typedef __attribute__((ext_vector_type(4))) float f32x4;

static __device__ __forceinline__ unsigned short f2bf(float f) {
    unsigned int u = __float_as_uint(f);
    u += 0x7FFF + ((u >> 16) & 1);   // RNE
    return (unsigned short)(u >> 16);
}
static __device__ __forceinline__ float bf2f(unsigned short h) {
    return __uint_as_float(((unsigned int)h) << 16);
}

// Shared memory union: GEMM path uses 32 KB of W fragments; partition path
// uses histogram + staging arrays (~36 KB). Union keeps 4 blocks/CU.
union SmemU {
    short8 wfl[2048];                      // [ks(8)][nt(4)][lane(64)] bf16 B-frags
    struct {
        int hcnt[NBUCKET];
        int excl[NBUCKET];
        int lcur[NBUCKET];
        int gbase[NBUCKET];
        int wsum[8];
        unsigned int staged[PTILE];
        unsigned short sbkt[PTILE];
    } p;
};

// ---------------------------------------------------------------------------
// Kernel 1 (fused): blocks [0, GEMM_BLOCKS) -> MFMA GEMM (xwb = bf16(x@W)),
// W fragments built in LDS per block (wfrag precompute kernel eliminated);
// blocks [GEMM_BLOCKS, GEMM_BLOCKS+NPT) -> edge partition into fixed-capacity
// bucket regions. 512 threads per block.
// ---------------------------------------------------------------------------
__global__ __launch_bounds__(512) void gemm_part_kernel(const float* __restrict__ x,
                                                        const float* __restrict__ W,
                                                        unsigned short* __restrict__ xwb,
                                                        const int* __restrict__ ei,
                                                        int* __restrict__ cnt,
                                                        unsigned int* __restrict__ packed_out) {
    __shared__ SmemU u;
    const int t = threadIdx.x;

    if (blockIdx.x < GEMM_BLOCKS) {
        // ---- stage W -> bf16 B-fragments in LDS (same layout as old wfrag) --
        for (int e = t; e < 2048; e += 512) {
            const int ks = e >> 8;
            const int nt = (e >> 6) & 3;
            const int l  = e & 63;
            const int q = l >> 4, m = l & 15;
            const int n = nt * 16 + m;
            const int k0 = ks * 32 + q * 8;
            short8 v;
            #pragma unroll
            for (int j = 0; j < 8; ++j) v[j] = (short)f2bf(W[(k0 + j) * HID_CH + n]);
            u.wfl[e] = v;
        }
        __syncthreads();

        // ---------------- GEMM path: 8 waves, each owns a 16x64 tile --------
        const int wv = t >> 6, lane = t & 63;
        const int q = lane >> 4, m = lane & 15;
        const int row0 = blockIdx.x * 128 + wv * 16;
        const int arow = row0 + m;
        const int arl = arow < N_NODES ? arow : N_NODES - 1;
        const float* xr = x + (size_t)arl * IN_CH + q * 8;

        f32x4 acc0 = {0.f,0.f,0.f,0.f}, acc1 = acc0, acc2 = acc0, acc3 = acc0;

        #pragma unroll
        for (int ks = 0; ks < 8; ++ks) {
            const float4 a0 = *(const float4*)(xr + ks * 32);
            const float4 a1 = *(const float4*)(xr + ks * 32 + 4);
            short8 af;
            af[0] = (short)f2bf(a0.x); af[1] = (short)f2bf(a0.y);
            af[2] = (short)f2bf(a0.z); af[3] = (short)f2bf(a0.w);
            af[4] = (short)f2bf(a1.x); af[5] = (short)f2bf(a1.y);
            af[6] = (short)f2bf(a1.z); af[7] = (short)f2bf(a1.w);
            const short8 b0 = u.wfl[(ks * 4 + 0) * 64 + lane];
            const short8 b1 = u.wfl[(ks * 4 + 1) * 64 + lane];
            const short8 b2 = u.wfl[(ks * 4 + 2) * 64 + lane];
            const short8 b3 = u.wfl[(ks * 4 + 3) * 64 + lane];
            acc0 = __builtin_amdgcn_mfma_f32_16x16x32_bf16(af, b0, acc0, 0, 0, 0);
            acc1 = __builtin_amdgcn_mfma_f32_16x16x32_bf16(af, b1, acc1, 0, 0, 0);
            acc2 = __builtin_amdgcn_mfma_f32_16x16x32_bf16(af, b2, acc2, 0, 0, 0);
            acc3 = __builtin_amdgcn_mfma_f32_16x16x32_bf16(af, b3, acc3, 0, 0, 0);
        }

        #pragma unroll
        for (int r = 0; r < 4; ++r) {
            const int row = row0 + q * 4 + r;
            if (row < N_NODES) {
                unsigned short* o = xwb + (size_t)row * HID_CH + m;
                o[0]  = f2bf(acc0[r]);
                o[16] = f2bf(acc1[r]);
                o[32] = f2bf(acc2[r]);
                o[48] = f2bf(acc3[r]);
            }
        }
        return;
    }

    // ---------------- partition path: tile of 4096 edges --------------------
    const int tile0 = (blockIdx.x - GEMM_BLOCKS) * PTILE;
    const int tcnt = min(PTILE, N_EDGES - tile0);

    for (int i = t; i < NBUCKET; i += 512) u.p.hcnt[i] = 0;
    __syncthreads();

    // int4 edge loads: 2 rounds x 512 threads x 4 edges. N_EDGES % 4 == 0, so
    // each int4 is fully in- or out-of-bounds. Order within tile is irrelevant.
    int es[8], ed[8];
    #pragma unroll
    for (int r = 0; r < 2; ++r) {
        const int base = tile0 + (r * 512 + t) * 4;
        if (base < N_EDGES) {
            const int4 s4 = *(const int4*)(ei + base);
            const int4 d4 = *(const int4*)(ei + N_EDGES + base);
            es[r*4+0] = s4.x; es[r*4+1] = s4.y; es[r*4+2] = s4.z; es[r*4+3] = s4.w;
            ed[r*4+0] = d4.x; ed[r*4+1] = d4.y; ed[r*4+2] = d4.z; ed[r*4+3] = d4.w;
        } else {
            #pragma unroll
            for (int j = 0; j < 4; ++j) es[r*4+j] = -1;
        }
    }
    #pragma unroll
    for (int i = 0; i < 8; ++i)
        if (es[i] >= 0) atomicAdd(&u.p.hcnt[ed[i] >> 6], 1);
    __syncthreads();

    // exclusive scan of 782 counts: pair-per-thread + shfl wave-scan
    const int b0 = 2 * t, b1 = 2 * t + 1;
    const int c0 = (b0 < NBUCKET) ? u.p.hcnt[b0] : 0;
    const int c1 = (b1 < NBUCKET) ? u.p.hcnt[b1] : 0;
    const int v = c0 + c1;
    int s = v;
    #pragma unroll
    for (int off = 1; off < 64; off <<= 1) {
        const int uu = __shfl_up(s, off, 64);
        if ((t & 63) >= off) s += uu;
    }
    if ((t & 63) == 63) u.p.wsum[t >> 6] = s;
    __syncthreads();
    if (t < 8) {
        const int ws = u.p.wsum[t];
        int si = ws;
        #pragma unroll
        for (int off = 1; off < 8; off <<= 1) {
            const int uu = __shfl_up(si, off, 64);
            if (t >= off) si += uu;
        }
        u.p.wsum[t] = si - ws;   // exclusive base for wave t
    }
    __syncthreads();
    const int ex = s - v + u.p.wsum[t >> 6];
    if (b0 < NBUCKET) {
        u.p.excl[b0] = ex; u.p.lcur[b0] = ex;
        if (c0 > 0) u.p.gbase[b0] = b0 * CAPB + atomicAdd(&cnt[b0], c0);
    }
    if (b1 < NBUCKET) {
        u.p.excl[b1] = ex + c0; u.p.lcur[b1] = ex + c0;
        if (c1 > 0) u.p.gbase[b1] = b1 * CAPB + atomicAdd(&cnt[b1], c1);
    }
    __syncthreads();

    #pragma unroll
    for (int i = 0; i < 8; ++i) {
        if (es[i] >= 0) {
            const int b = ed[i] >> 6;
            const int pos = atomicAdd(&u.p.lcur[b], 1);
            u.p.staged[pos] = ((unsigned int)(ed[i] & 63) << 16) | (unsigned int)es[i];
            u.p.sbkt[pos] = (unsigned short)b;
        }
    }
    __syncthreads();

    #pragma unroll
    for (int i = 0; i < 8; ++i) {
        const int idx = t + i * 512;
        if (idx < tcnt) {
            const int b = u.p.sbkt[idx];
            packed_out[u.p.gbase[b] + (idx - u.p.excl[b])] = u.p.staged[idx];
        }
    }
}

// ---------------------------------------------------------------------------
// Kernel 2: per-bucket aggregate (64 nodes). In-LDS counting sort (wave-0
// shfl scan; packed read twice from L2), then SLOT-OWNS-NODE gather:
// 512 threads = 64 slots x 8 lanes; slot s owns node s exclusively.
// Each lane covers 8 channels via short8 (dwordx4) loads and accumulates in
// registers only — no cross-slot shuffles, no LDS accumulator, no separate
// epilogue pass. Bias + PReLU fused into the final coalesced store.
// ---------------------------------------------------------------------------
__global__ __launch_bounds__(512) void aggregate_kernel(const unsigned short* __restrict__ xwb,
                                                        const unsigned int* __restrict__ packed,
                                                        const int* __restrict__ cnt,
                                                        const float* __restrict__ bias,
                                                        const float* __restrict__ prelu_a,
                                                        float* __restrict__ out) {
    __shared__ unsigned short ssrc[CAP];      // 4 KB
    __shared__ int hcnt[AG_ROWS];
    __shared__ int hexcl[AG_ROWS];
    __shared__ int hcur[AG_ROWS];

    const int b = blockIdx.x;
    const int t = threadIdx.x;
    const int beg = b * CAPB;
    const int total = min(cnt[b], CAP);

    if (t < AG_ROWS) hcnt[t] = 0;
    __syncthreads();

    // histogram pass (packed is L2-resident)
    for (int i = t; i < total; i += 512)
        atomicAdd(&hcnt[packed[beg + i] >> 16], 1);
    __syncthreads();

    // exclusive scan of 64 counts by wave 0 (shfl)
    if (t < AG_ROWS) {
        const int v = hcnt[t];
        int s = v;
        #pragma unroll
        for (int off = 1; off < 64; off <<= 1) {
            const int u = __shfl_up(s, off, 64);
            if (t >= off) s += u;
        }
        hexcl[t] = s - v;
        hcur[t]  = s - v;
    }
    __syncthreads();

    // reorder pass: packed re-read, scatter src ids into node-sorted runs
    for (int i = t; i < total; i += 512) {
        const unsigned int p = packed[beg + i];
        const int pos = atomicAdd(&hcur[p >> 16], 1);
        ssrc[pos] = (unsigned short)(p & 0xFFFFu);
    }
    __syncthreads();

    // slot-owns-node gather: slot sl (8 lanes) handles node sl entirely.
    const int sl = t >> 3;           // 0..63
    const int li = t & 7;
    const int c0 = li * 8;           // channel base
    const int rb = hexcl[sl];
    const int re = rb + hcnt[sl];

    float a[8];
    #pragma unroll
    for (int j = 0; j < 8; ++j) a[j] = 0.f;

    int i = rb;
    for (; i + 3 < re; i += 4) {     // 4 rows in flight per slot
        const int e0 = ssrc[i + 0];
        const int e1 = ssrc[i + 1];
        const int e2 = ssrc[i + 2];
        const int e3 = ssrc[i + 3];
        const short8 v0 = *(const short8*)(xwb + (size_t)e0 * HID_CH + c0);
        const short8 v1 = *(const short8*)(xwb + (size_t)e1 * HID_CH + c0);
        const short8 v2 = *(const short8*)(xwb + (size_t)e2 * HID_CH + c0);
        const short8 v3 = *(const short8*)(xwb + (size_t)e3 * HID_CH + c0);
        #pragma unroll
        for (int j = 0; j < 8; ++j)
            a[j] += (bf2f((unsigned short)v0[j]) + bf2f((unsigned short)v1[j]))
                  + (bf2f((unsigned short)v2[j]) + bf2f((unsigned short)v3[j]));
    }
    for (; i < re; ++i) {
        const int e0 = ssrc[i];
        const short8 v0 = *(const short8*)(xwb + (size_t)e0 * HID_CH + c0);
        #pragma unroll
        for (int j = 0; j < 8; ++j) a[j] += bf2f((unsigned short)v0[j]);
    }

    // fused bias + PReLU epilogue, coalesced 2x float4 store per lane
    const int node = b * AG_ROWS + sl;
    if (node < N_NODES) {
        const float4 bb0 = *(const float4*)(bias + c0);
        const float4 bb1 = *(const float4*)(bias + c0 + 4);
        const float4 aa0 = *(const float4*)(prelu_a + c0);
        const float4 aa1 = *(const float4*)(prelu_a + c0 + 4);
        float4 r0, r1;
        r0.x = a[0] + bb0.x; r0.x = r0.x > 0.f ? r0.x : aa0.x * r0.x;
        r0.y = a[1] + bb0.y; r0.y = r0.y > 0.f ? r0.y : aa0.y * r0.y;
        r0.z = a[2] + bb0.z; r0.z = r0.z > 0.f ? r0.z : aa0.z * r0.z;
        r0.w = a[3] + bb0.w; r0.w = r0.w > 0.f ? r0.w : aa0.w * r0.w;
        r1.x = a[4] + bb1.x; r1.x = r1.x > 0.f ? r1.x : aa1.x * r1.x;
        r1.y = a[5] + bb1.y; r1.y = r1.y > 0.f ? r1.y : aa1.y * r1.y;
        r1.z = a[6] + bb1.z; r1.z = r1.z > 0.f ? r1.z : aa1.z * r1.z;
        r1.w = a[7] + bb1.w; r1.w = r1.w > 0.f ? r1.w : aa1.w * r1.w;
        float4* op = (float4*)(out + (size_t)node * HID_CH + c0);
        op[0] = r0;
        op[1] = r1;
    }
}

extern "C" void kernel_launch(void* const* d_in, const int* in_sizes, int n_in,
                              void* d_out, int out_size, void* d_ws, size_t ws_size,
                              hipStream_t stream) {
    const float* x       = (const float*)d_in[0];
    const int*   ei      = (const int*)d_in[1];   // [2, E]: src row then dst row
    const float* W       = (const float*)d_in[2];
    const float* bias    = (const float*)d_in[3];
    const float* prelu_a = (const float*)d_in[4];
    float* out = (float*)d_out;

    // workspace layout (16B-aligned)
    char* w = (char*)d_ws;
    unsigned short* xwb    = (unsigned short*)(w);             // 6,400,000 B
    int*            cnt    = (int*)(w + 6400000);              //     3,128 B
    unsigned int*   packed = (unsigned int*)(w + 6403200);     // 4,804,608 B (782*1536*4)

    // 0) zero bucket counters (graph-capturable async memset)
    hipMemsetAsync(cnt, 0, NBUCKET * sizeof(int), stream);

    // 1) fused: gemm (blocks 0..390, W-frags built in LDS) + edge partition
    gemm_part_kernel<<<GEMM_BLOCKS + NPT, 512, 0, stream>>>(x, W, xwb, ei, cnt, packed);

    // 2) per-bucket sort + slot-owns-node aggregate + bias + PReLU
    aggregate_kernel<<<NBUCKET, 512, 0, stream>>>(xwb, packed, cnt, bias, prelu_a, out);
}

// Round 2
// 125.166 us; speedup vs baseline: 1.0408x; 1.0021x over previous
//
#include <hip/hip_runtime.h>

#define N_NODES 50000
#define IN_CH   256
#define HID_CH  64
#define N_EDGES 800000

#define AG_ROWS 64           // nodes per bucket
#define NBUCKET 782          // ceil(50000 / 64)
#define CAPB    1536         // fixed capacity per bucket region (~16 sigma)
#define PTILE   4096         // edges per partition tile
#define NPT     196          // ceil(800000 / 4096)
#define GEMM_BLOCKS 391      // ceil(50000 / 128) at 128 rows per 512-thr block
#define CAP     2048         // aggregate staging capacity (> CAPB)

typedef __attribute__((ext_vector_type(8))) short short8;
typedef __attribute__((ext_vector_type(4))) float f32x4;

static __device__ __forceinline__ float bf2f(unsigned short h) {
    return __uint_as_float(((unsigned int)h) << 16);
}
// packed f32x2 -> bf16x2 (RNE), 1 inst for 2 elements (vs 3-inst manual RNE)
static __device__ __forceinline__ unsigned int cvt_pk(float lo, float hi) {
    unsigned int r;
    asm("v_cvt_pk_bf16_f32 %0, %1, %2" : "=v"(r) : "v"(lo), "v"(hi));
    return r;
}

// Shared memory union: GEMM path uses 32 KB of W fragments; partition path
// uses histogram + staging arrays (~36 KB). Union keeps 4 blocks/CU.
union SmemU {
    short8 wfl[2048];                      // [ks(8)][nt(4)][lane(64)] bf16 B-frags
    struct {
        int hcnt[NBUCKET];
        int excl[NBUCKET];
        int lcur[NBUCKET];
        int gbase[NBUCKET];
        int wsum[8];
        unsigned int staged[PTILE];
        unsigned short sbkt[PTILE];
    } p;
};

// ---------------------------------------------------------------------------
// Kernel 1 (fused): GEMM blocks (xwb = bf16(x@W), W-frags staged in LDS) and
// edge-partition blocks INTERLEAVED over blockIdx (odd/even) so the x-stream
// and ei-stream overlap from dispatch start. 512 threads per block.
// ---------------------------------------------------------------------------
__global__ __launch_bounds__(512, 4) void gemm_part_kernel(const float* __restrict__ x,
                                                           const float* __restrict__ W,
                                                           unsigned short* __restrict__ xwb,
                                                           const int* __restrict__ ei,
                                                           int* __restrict__ cnt,
                                                           unsigned int* __restrict__ packed_out) {
    __shared__ SmemU u;
    const int t = threadIdx.x;
    const int bid = blockIdx.x;

    // role interleave: odd bids (first 392) are partition, rest GEMM
    int pid = -1, gid = -1;
    if ((bid & 1) && (bid >> 1) < NPT) pid = bid >> 1;
    else gid = (bid < 2 * NPT) ? (bid >> 1) : (bid - NPT);

    if (gid >= 0) {
        // ---- stage W -> bf16 B-fragments in LDS (cvt_pk: 4 insts / 8 elems) --
        for (int e = t; e < 2048; e += 512) {
            const int ks = e >> 8;
            const int nt = (e >> 6) & 3;
            const int l  = e & 63;
            const int q = l >> 4, m = l & 15;
            const int n = nt * 16 + m;
            const int k0 = ks * 32 + q * 8;
            const float* wp = W + (size_t)k0 * HID_CH + n;
            uint4 v;
            v.x = cvt_pk(wp[0 * HID_CH], wp[1 * HID_CH]);
            v.y = cvt_pk(wp[2 * HID_CH], wp[3 * HID_CH]);
            v.z = cvt_pk(wp[4 * HID_CH], wp[5 * HID_CH]);
            v.w = cvt_pk(wp[6 * HID_CH], wp[7 * HID_CH]);
            ((uint4*)u.wfl)[e] = v;
        }
        __syncthreads();

        // ---------------- GEMM path: 8 waves, each owns a 16x64 tile --------
        const int wv = t >> 6, lane = t & 63;
        const int q = lane >> 4, m = lane & 15;
        const int row0 = gid * 128 + wv * 16;
        const int arow = row0 + m;
        const int arl = arow < N_NODES ? arow : N_NODES - 1;
        const float* xr = x + (size_t)arl * IN_CH + q * 8;

        // explicit 16-deep A prefetch: 16 dwordx4 in flight per wave (HBM-cold
        // after the workspace poison fill; latency-hiding is the lever here)
        float4 areg[16];
        #pragma unroll
        for (int ks = 0; ks < 8; ++ks) {
            areg[2 * ks]     = *(const float4*)(xr + ks * 32);
            areg[2 * ks + 1] = *(const float4*)(xr + ks * 32 + 4);
        }

        f32x4 acc0 = {0.f,0.f,0.f,0.f}, acc1 = acc0, acc2 = acc0, acc3 = acc0;

        #pragma unroll
        for (int ks = 0; ks < 8; ++ks) {
            short8 af;
            unsigned int* afu = (unsigned int*)&af;
            afu[0] = cvt_pk(areg[2 * ks].x,     areg[2 * ks].y);
            afu[1] = cvt_pk(areg[2 * ks].z,     areg[2 * ks].w);
            afu[2] = cvt_pk(areg[2 * ks + 1].x, areg[2 * ks + 1].y);
            afu[3] = cvt_pk(areg[2 * ks + 1].z, areg[2 * ks + 1].w);
            const short8 b0 = u.wfl[(ks * 4 + 0) * 64 + lane];
            const short8 b1 = u.wfl[(ks * 4 + 1) * 64 + lane];
            const short8 b2 = u.wfl[(ks * 4 + 2) * 64 + lane];
            const short8 b3 = u.wfl[(ks * 4 + 3) * 64 + lane];
            acc0 = __builtin_amdgcn_mfma_f32_16x16x32_bf16(af, b0, acc0, 0, 0, 0);
            acc1 = __builtin_amdgcn_mfma_f32_16x16x32_bf16(af, b1, acc1, 0, 0, 0);
            acc2 = __builtin_amdgcn_mfma_f32_16x16x32_bf16(af, b2, acc2, 0, 0, 0);
            acc3 = __builtin_amdgcn_mfma_f32_16x16x32_bf16(af, b3, acc3, 0, 0, 0);
        }

        #pragma unroll
        for (int r = 0; r < 4; ++r) {
            const int row = row0 + q * 4 + r;
            if (row < N_NODES) {
                unsigned short* o = xwb + (size_t)row * HID_CH + m;
                const unsigned int p01 = cvt_pk(acc0[r], acc1[r]);
                const unsigned int p23 = cvt_pk(acc2[r], acc3[r]);
                o[0]  = (unsigned short)(p01 & 0xFFFFu);
                o[16] = (unsigned short)(p01 >> 16);
                o[32] = (unsigned short)(p23 & 0xFFFFu);
                o[48] = (unsigned short)(p23 >> 16);
            }
        }
        return;
    }

    // ---------------- partition path: tile of 4096 edges --------------------
    const int tile0 = pid * PTILE;
    const int tcnt = min(PTILE, N_EDGES - tile0);

    for (int i = t; i < NBUCKET; i += 512) u.p.hcnt[i] = 0;
    __syncthreads();

    // int4 edge loads: 2 rounds x 512 threads x 4 edges. N_EDGES % 4 == 0, so
    // each int4 is fully in- or out-of-bounds. Order within tile is irrelevant.
    int es[8], ed[8];
    #pragma unroll
    for (int r = 0; r < 2; ++r) {
        const int base = tile0 + (r * 512 + t) * 4;
        if (base < N_EDGES) {
            const int4 s4 = *(const int4*)(ei + base);
            const int4 d4 = *(const int4*)(ei + N_EDGES + base);
            es[r*4+0] = s4.x; es[r*4+1] = s4.y; es[r*4+2] = s4.z; es[r*4+3] = s4.w;
            ed[r*4+0] = d4.x; ed[r*4+1] = d4.y; ed[r*4+2] = d4.z; ed[r*4+3] = d4.w;
        } else {
            #pragma unroll
            for (int j = 0; j < 4; ++j) es[r*4+j] = -1;
        }
    }
    #pragma unroll
    for (int i = 0; i < 8; ++i)
        if (es[i] >= 0) atomicAdd(&u.p.hcnt[ed[i] >> 6], 1);
    __syncthreads();

    // exclusive scan of 782 counts: pair-per-thread + shfl wave-scan
    const int b0 = 2 * t, b1 = 2 * t + 1;
    const int c0 = (b0 < NBUCKET) ? u.p.hcnt[b0] : 0;
    const int c1 = (b1 < NBUCKET) ? u.p.hcnt[b1] : 0;
    const int v = c0 + c1;
    int s = v;
    #pragma unroll
    for (int off = 1; off < 64; off <<= 1) {
        const int uu = __shfl_up(s, off, 64);
        if ((t & 63) >= off) s += uu;
    }
    if ((t & 63) == 63) u.p.wsum[t >> 6] = s;
    __syncthreads();
    if (t < 8) {
        const int ws = u.p.wsum[t];
        int si = ws;
        #pragma unroll
        for (int off = 1; off < 8; off <<= 1) {
            const int uu = __shfl_up(si, off, 64);
            if (t >= off) si += uu;
        }
        u.p.wsum[t] = si - ws;   // exclusive base for wave t
    }
    __syncthreads();
    const int ex = s - v + u.p.wsum[t >> 6];
    if (b0 < NBUCKET) {
        u.p.excl[b0] = ex; u.p.lcur[b0] = ex;
        if (c0 > 0) u.p.gbase[b0] = b0 * CAPB + atomicAdd(&cnt[b0], c0);
    }
    if (b1 < NBUCKET) {
        u.p.excl[b1] = ex + c0; u.p.lcur[b1] = ex + c0;
        if (c1 > 0) u.p.gbase[b1] = b1 * CAPB + atomicAdd(&cnt[b1], c1);
    }
    __syncthreads();

    #pragma unroll
    for (int i = 0; i < 8; ++i) {
        if (es[i] >= 0) {
            const int b = ed[i] >> 6;
            const int pos = atomicAdd(&u.p.lcur[b], 1);
            u.p.staged[pos] = ((unsigned int)(ed[i] & 63) << 16) | (unsigned int)es[i];
            u.p.sbkt[pos] = (unsigned short)b;
        }
    }
    __syncthreads();

    #pragma unroll
    for (int i = 0; i < 8; ++i) {
        const int idx = t + i * 512;
        if (idx < tcnt) {
            const int b = u.p.sbkt[idx];
            packed_out[u.p.gbase[b] + (idx - u.p.excl[b])] = u.p.staged[idx];
        }
    }
}

// ---------------------------------------------------------------------------
// Kernel 2: per-bucket aggregate (64 nodes). In-LDS counting sort (wave-0
// shfl scan; packed read twice from L2), then SLOT-OWNS-NODE gather:
// 512 threads = 64 slots x 8 lanes; slot s owns node s exclusively.
// Each lane covers 8 channels via short8 (dwordx4) loads and accumulates in
// registers only. Main loop 8-deep ILP (runs avg ~16, L2-latency-bound).
// Bias + PReLU fused into the final coalesced store.
// ---------------------------------------------------------------------------
__global__ __launch_bounds__(512) void aggregate_kernel(const unsigned short* __restrict__ xwb,
                                                        const unsigned int* __restrict__ packed,
                                                        const int* __restrict__ cnt,
                                                        const float* __restrict__ bias,
                                                        const float* __restrict__ prelu_a,
                                                        float* __restrict__ out) {
    __shared__ unsigned short ssrc[CAP];      // 4 KB
    __shared__ int hcnt[AG_ROWS];
    __shared__ int hexcl[AG_ROWS];
    __shared__ int hcur[AG_ROWS];

    const int b = blockIdx.x;
    const int t = threadIdx.x;
    const int beg = b * CAPB;
    const int total = min(cnt[b], CAP);

    if (t < AG_ROWS) hcnt[t] = 0;
    __syncthreads();

    // histogram pass (packed is L2-resident)
    for (int i = t; i < total; i += 512)
        atomicAdd(&hcnt[packed[beg + i] >> 16], 1);
    __syncthreads();

    // exclusive scan of 64 counts by wave 0 (shfl)
    if (t < AG_ROWS) {
        const int v = hcnt[t];
        int s = v;
        #pragma unroll
        for (int off = 1; off < 64; off <<= 1) {
            const int u = __shfl_up(s, off, 64);
            if (t >= off) s += u;
        }
        hexcl[t] = s - v;
        hcur[t]  = s - v;
    }
    __syncthreads();

    // reorder pass: packed re-read, scatter src ids into node-sorted runs
    for (int i = t; i < total; i += 512) {
        const unsigned int p = packed[beg + i];
        const int pos = atomicAdd(&hcur[p >> 16], 1);
        ssrc[pos] = (unsigned short)(p & 0xFFFFu);
    }
    __syncthreads();

    // slot-owns-node gather: slot sl (8 lanes) handles node sl entirely.
    const int sl = t >> 3;           // 0..63
    const int li = t & 7;
    const int c0 = li * 8;           // channel base
    const int rb = hexcl[sl];
    const int re = rb + hcnt[sl];

    float a[8];
    #pragma unroll
    for (int j = 0; j < 8; ++j) a[j] = 0.f;

    int i = rb;
    for (; i + 7 < re; i += 8) {     // 8 rows in flight per slot
        short8 vv[8];
        #pragma unroll
        for (int r = 0; r < 8; ++r) {
            const int e = ssrc[i + r];
            vv[r] = *(const short8*)(xwb + (size_t)e * HID_CH + c0);
        }
        #pragma unroll
        for (int r = 0; r < 8; ++r)
            #pragma unroll
            for (int j = 0; j < 8; ++j)
                a[j] += bf2f((unsigned short)vv[r][j]);
    }
    for (; i + 3 < re; i += 4) {     // 4-deep remainder
        short8 vv[4];
        #pragma unroll
        for (int r = 0; r < 4; ++r) {
            const int e = ssrc[i + r];
            vv[r] = *(const short8*)(xwb + (size_t)e * HID_CH + c0);
        }
        #pragma unroll
        for (int r = 0; r < 4; ++r)
            #pragma unroll
            for (int j = 0; j < 8; ++j)
                a[j] += bf2f((unsigned short)vv[r][j]);
    }
    for (; i < re; ++i) {
        const int e0 = ssrc[i];
        const short8 v0 = *(const short8*)(xwb + (size_t)e0 * HID_CH + c0);
        #pragma unroll
        for (int j = 0; j < 8; ++j) a[j] += bf2f((unsigned short)v0[j]);
    }

    // fused bias + PReLU epilogue, coalesced 2x float4 store per lane
    const int node = b * AG_ROWS + sl;
    if (node < N_NODES) {
        const float4 bb0 = *(const float4*)(bias + c0);
        const float4 bb1 = *(const float4*)(bias + c0 + 4);
        const float4 aa0 = *(const float4*)(prelu_a + c0);
        const float4 aa1 = *(const float4*)(prelu_a + c0 + 4);
        float4 r0, r1;
        r0.x = a[0] + bb0.x; r0.x = r0.x > 0.f ? r0.x : aa0.x * r0.x;
        r0.y = a[1] + bb0.y; r0.y = r0.y > 0.f ? r0.y : aa0.y * r0.y;
        r0.z = a[2] + bb0.z; r0.z = r0.z > 0.f ? r0.z : aa0.z * r0.z;
        r0.w = a[3] + bb0.w; r0.w = r0.w > 0.f ? r0.w : aa0.w * r0.w;
        r1.x = a[4] + bb1.x; r1.x = r1.x > 0.f ? r1.x : aa1.x * r1.x;
        r1.y = a[5] + bb1.y; r1.y = r1.y > 0.f ? r1.y : aa1.y * r1.y;
        r1.z = a[6] + bb1.z; r1.z = r1.z > 0.f ? r1.z : aa1.z * r1.z;
        r1.w = a[7] + bb1.w; r1.w = r1.w > 0.f ? r1.w : aa1.w * r1.w;
        float4* op = (float4*)(out + (size_t)node * HID_CH + c0);
        op[0] = r0;
        op[1] = r1;
    }
}

extern "C" void kernel_launch(void* const* d_in, const int* in_sizes, int n_in,
                              void* d_out, int out_size, void* d_ws, size_t ws_size,
                              hipStream_t stream) {
    const float* x       = (const float*)d_in[0];
    const int*   ei      = (const int*)d_in[1];   // [2, E]: src row then dst row
    const float* W       = (const float*)d_in[2];
    const float* bias    = (const float*)d_in[3];
    const float* prelu_a = (const float*)d_in[4];
    float* out = (float*)d_out;

    // workspace layout (16B-aligned)
    char* w = (char*)d_ws;
    unsigned short* xwb    = (unsigned short*)(w);             // 6,400,000 B
    int*            cnt    = (int*)(w + 6400000);              //     3,128 B
    unsigned int*   packed = (unsigned int*)(w + 6403200);     // 4,804,608 B (782*1536*4)

    // 0) zero bucket counters (graph-capturable async memset)
    hipMemsetAsync(cnt, 0, NBUCKET * sizeof(int), stream);

    // 1) fused + interleaved: gemm (391 blocks) + edge partition (196 blocks)
    gemm_part_kernel<<<GEMM_BLOCKS + NPT, 512, 0, stream>>>(x, W, xwb, ei, cnt, packed);

    // 2) per-bucket sort + slot-owns-node aggregate + bias + PReLU
    aggregate_kernel<<<NBUCKET, 512, 0, stream>>>(xwb, packed, cnt, bias, prelu_a, out);
}